// Round 2
// baseline (1144.102 us; speedup 1.0000x reference)
//
#include <hip/hip_runtime.h>

#define NB 4
#define NC 6
#define NF 257
#define NT 2000
#define NG (NB * NF)        // 1028 (b,f) groups
#define NPAIR 15
#define NACC 74             // [0..5] s_diag, [6..11] n_diag, [12+4q..] s_re,s_im,n_re,n_im, [72] sum_ms, [73] sum_mn
#define NCHUNK 4
#define TCH (NT / NCHUNK)   // 500 t per chunk
#define NP2C (TCH / 2)      // 250 float2 per chunk
#define NP2G (NT / 2)       // 1000 float2 per group
#define BLK 256
#define NJ 4                // apply phase: float2 per thread (4*256 >= 1000)
#define CS  (NF * NT)       // channel stride (floats)
#define CS2 (CS / 2)        // channel stride (float2)

typedef float nfloat4 __attribute__((ext_vector_type(4)));

// DPP row-shift-right add: lane i += lane (i-N) within its 16-lane row
// (0 beyond row edge). After shr8+shr4+shr2: lane14 = row evens-sum,
// lane15 = row odds-sum (HW-verified in prior session).
template<int CTRL>
__device__ __forceinline__ float dpp_add(float v) {
    int s = __builtin_amdgcn_update_dpp(0, __builtin_bit_cast(int, v), CTRL, 0xF, 0xF, true);
    return v + __builtin_bit_cast(float, s);
}

// upper-triangle pair index for c < e (enumeration matches PC/PE tables)
__device__ __forceinline__ int qidx(int c, int e) {
    return c * (2 * NC - 1 - c) / 2 + (e - c - 1);
}

// ---------------- One-pass MVDR: 4112 blocks, last-arriver does tail -------
// Every block: psd partials for its (group, chunk) at full 4112-block TLP
// (the proven round-0 structure), atomicAdd into per-group accumulator.
// The 4th arriver of each group: reduce -> LU solve (lanes 0..5) -> apply w
// over the full 2000-t group (spec is L3-hot). Non-last blocks exit early,
// so psd of later groups overlaps apply of earlier ones in ONE dispatch.
__global__ __launch_bounds__(BLK) void mvdr_onepass(
    const float* __restrict__ sr, const float* __restrict__ si,
    const float* __restrict__ ms, const float* __restrict__ mn,
    float* __restrict__ out,
    float* __restrict__ finbuf,   // [NG][NACC] zeroed at launch
    int*   __restrict__ cnt)      // [NG] zeroed at launch
{
    constexpr int PC[NPAIR] = {0,0,0,0,0,1,1,1,1,2,2,2,3,3,4};
    constexpr int PE[NPAIR] = {1,2,3,4,5,2,3,4,5,3,4,5,4,5,5};

    const int bx  = blockIdx.x;
    const int g   = bx >> 2;
    const int b   = g / NF;
    const int f   = g - b * NF;
    const int tb2 = (bx & 3) * NP2C;           // this chunk's float2 offset
    const int sbase = b * NC * CS + f * NT;    // group spec base (floats)
    const int tid = threadIdx.x;

    const float2* s2r = (const float2*)(sr + sbase);
    const float2* s2i = (const float2*)(si + sbase);
    const float2* m2s = (const float2*)(ms + g * NT) + tb2;
    const float2* m2n = (const float2*)(mn + g * NT) + tb2;

    float acc[NACC];
    #pragma unroll
    for (int i = 0; i < NACC; i++) acc[i] = 0.f;

    // ---------------- Phase 1: psd partials for this chunk (1 float2/thread)
    {
        const bool act = tid < NP2C;
        const int  p   = act ? tid : 0;
        const int  ps  = tb2 + p;
        float wms[2], wmn[2], rr[NC][2], ii[NC][2];
        {
            const float2 t0 = m2s[p];
            wms[0] = t0.x; wms[1] = t0.y;
            const float2 t1 = m2n[p];
            wmn[0] = t1.x; wmn[1] = t1.y;
        }
        #pragma unroll
        for (int c = 0; c < NC; c++) {
            const float2 tr = s2r[c * CS2 + ps];
            rr[c][0] = tr.x; rr[c][1] = tr.y;
            const float2 ti = s2i[c * CS2 + ps];
            ii[c][0] = ti.x; ii[c][1] = ti.y;
        }
        if (!act) { wms[0] = wms[1] = wmn[0] = wmn[1] = 0.f; }
        #pragma unroll
        for (int k = 0; k < 2; k++) { acc[72] += wms[k]; acc[73] += wmn[k]; }
        #pragma unroll
        for (int c = 0; c < NC; c++) {
            #pragma unroll
            for (int k = 0; k < 2; k++) {
                const float d = rr[c][k] * rr[c][k] + ii[c][k] * ii[c][k];
                acc[c]     += d * wms[k];
                acc[6 + c] += d * wmn[k];
            }
        }
        #pragma unroll
        for (int q = 0; q < NPAIR; q++) {
            const int c = PC[q], e = PE[q];
            #pragma unroll
            for (int k = 0; k < 2; k++) {
                const float cr = rr[c][k] * rr[e][k] + ii[c][k] * ii[e][k];
                const float ci = ii[c][k] * rr[e][k] - rr[c][k] * ii[e][k];
                acc[12 + 4 * q + 0] += cr * wms[k];
                acc[12 + 4 * q + 1] += ci * wms[k];
                acc[12 + 4 * q + 2] += cr * wmn[k];
                acc[12 + 4 * q + 3] += ci * wmn[k];
            }
        }
    }

    // ---------------- Phase 2: in-block reduction (DPP + LDS) --------------
    #pragma unroll
    for (int i = 0; i < NACC; i++) {
        float v = acc[i];
        v = dpp_add<0x118>(v);   // row_shr:8
        v = dpp_add<0x114>(v);   // row_shr:4
        v = dpp_add<0x112>(v);   // row_shr:2
        acc[i] = v;
    }

    __shared__ float red[32][NACC];
    __shared__ int lastflag;

    const int lane16 = tid & 15;
    const int ridx   = ((tid >> 4) << 1) | (lane16 & 1);  // 0..31
    if (lane16 >= 14) {
        #pragma unroll
        for (int i = 0; i < NACC; i++) red[ridx][i] = acc[i];
    }
    __syncthreads();

    if (tid < NACC) {
        float s = 0.f;
        #pragma unroll
        for (int r = 0; r < 32; r++) s += red[r][tid];
        atomicAdd(&finbuf[g * NACC + tid], s);   // device-scope, XCD-safe
    }
    __threadfence();     // release: partial adds ordered before counter bump
    __syncthreads();
    if (tid == 0) {
        lastflag = (atomicAdd(&cnt[g], 1) == NCHUNK - 1);
    }
    __syncthreads();
    if (!lastflag) return;   // non-last blocks free their wave slots
    __threadfence();         // acquire

    // ---------------- Phase 2b: group reduction (atomic coherent reads) ----
    __shared__ float fin[NACC];
    __shared__ float sdr[NC], sdi[NC];
    __shared__ float wsh[2 * NC];
    if (tid < NACC) fin[tid] = atomicAdd(&finbuf[g * NACC + tid], 0.0f);
    __syncthreads();

    // ---------------- Phase 2c: in-block solve (lanes 0..5) ----------------
    float xr[NC], xi[NC];
    if (tid < NC) {
        const float invS = 1.f / (fin[72] + 1e-15f);
        const float invN = 1.f / (fin[73] + 1e-15f);

        // A = normalized psd_n + eps*I
        float Ar[NC][NC], Ai[NC][NC];
        #pragma unroll
        for (int c = 0; c < NC; c++) { Ar[c][c] = fin[6 + c] * invN; Ai[c][c] = 0.f; }
        #pragma unroll
        for (int q = 0; q < NPAIR; q++) {
            const int c = PC[q], e = PE[q];
            const float nre = fin[12 + 4 * q + 2] * invN;
            const float nim = fin[12 + 4 * q + 3] * invN;
            Ar[c][e] = nre;  Ai[c][e] = nim;
            Ar[e][c] = nre;  Ai[e][c] = -nim;
        }
        {
            float trn = 0.f;
            #pragma unroll
            for (int c = 0; c < NC; c++) trn += Ar[c][c];
            const float eps = trn * 1e-7f + 1e-8f;
            #pragma unroll
            for (int c = 0; c < NC; c++) Ar[c][c] += eps;
        }

        // In-place unpivoted LU (redundant on each of the 6 lanes)
        #pragma unroll
        for (int k = 0; k < NC; k++) {
            const float dr = Ar[k][k], di = Ai[k][k];
            const float idn = 1.f / (dr * dr + di * di);
            const float pr = dr * idn, pi = -di * idn;
            #pragma unroll
            for (int i = k + 1; i < NC; i++) {
                const float lr = Ar[i][k] * pr - Ai[i][k] * pi;
                const float li = Ar[i][k] * pi + Ai[i][k] * pr;
                Ar[i][k] = lr; Ai[i][k] = li;
                #pragma unroll
                for (int j = k + 1; j < NC; j++) {
                    Ar[i][j] -= lr * Ar[k][j] - li * Ai[k][j];
                    Ai[i][j] -= lr * Ai[k][j] + li * Ar[k][j];
                }
            }
        }

        // RHS = column `tid` of normalized psd_s (i compile-time, tid runtime)
        #pragma unroll
        for (int i = 0; i < NC; i++) {
            if (i == tid)      { xr[i] = fin[i] * invS;  xi[i] = 0.f; }
            else if (i < tid)  { const int q = qidx(i, tid);
                                 xr[i] = fin[12 + 4 * q] * invS;  xi[i] =  fin[13 + 4 * q] * invS; }
            else               { const int q = qidx(tid, i);
                                 xr[i] = fin[12 + 4 * q] * invS;  xi[i] = -fin[13 + 4 * q] * invS; }
        }
        // forward substitution
        #pragma unroll
        for (int i = 1; i < NC; i++) {
            #pragma unroll
            for (int k = 0; k < NC - 1; k++) if (k < i) {
                xr[i] -= Ar[i][k] * xr[k] - Ai[i][k] * xi[k];
                xi[i] -= Ar[i][k] * xi[k] + Ai[i][k] * xr[k];
            }
        }
        // backward substitution
        #pragma unroll
        for (int i = NC - 1; i >= 0; i--) {
            #pragma unroll
            for (int k = 0; k < NC; k++) if (k > i) {
                xr[i] -= Ar[i][k] * xr[k] - Ai[i][k] * xi[k];
                xi[i] -= Ar[i][k] * xi[k] + Ai[i][k] * xr[k];
            }
            const float dr = Ar[i][i], di = Ai[i][i];
            const float idn = 1.f / (dr * dr + di * di);
            const float pr = dr * idn, pi = -di * idn;
            const float t0 = xr[i] * pr - xi[i] * pi;
            xi[i] = xr[i] * pi + xi[i] * pr;
            xr[i] = t0;
        }
        // own diagonal element, extracted without runtime register indexing
        float dgr = xr[0], dgi = xi[0];
        #pragma unroll
        for (int i = 1; i < NC; i++) if (tid == i) { dgr = xr[i]; dgi = xi[i]; }
        sdr[tid] = dgr; sdi[tid] = dgi;
    }
    __syncthreads();

    if (tid == 0) {
        float trr = 1e-8f, tri = 0.f;   // TIK_EPS on real part of trace
        #pragma unroll
        for (int c = 0; c < NC; c++) { trr += sdr[c]; tri += sdi[c]; }
        const float idn = 1.f / (trr * trr + tri * tri);
        #pragma unroll
        for (int c = 0; c < NC; c++) {
            // lane 0's xr/xi == column 0 of the numerator (persists across barrier)
            const float wre = (xr[c] * trr + xi[c] * tri) * idn;
            const float wim = (xi[c] * trr - xr[c] * tri) * idn;
            wsh[c]     = wre;    // conj(w): real
            wsh[6 + c] = -wim;   // conj(w): imag
        }
    }
    __syncthreads();

    // ---------------- Phase 3: apply w over the FULL group (L3-hot spec) ---
    float wr[NC], wi[NC];
    #pragma unroll
    for (int c = 0; c < NC; c++) { wr[c] = wsh[c]; wi[c] = wsh[6 + c]; }

    nfloat4* o4 = (nfloat4*)(out + 2 * g * NT);
    #pragma unroll
    for (int j = 0; j < NJ; j++) {
        const int p = j * BLK + tid;
        if (p < NP2G) {
            float rr[NC][2], ii[NC][2];
            #pragma unroll
            for (int c = 0; c < NC; c++) {
                const float2 tr = s2r[c * CS2 + p];
                rr[c][0] = tr.x; rr[c][1] = tr.y;
                const float2 ti = s2i[c * CS2 + p];
                ii[c][0] = ti.x; ii[c][1] = ti.y;
            }
            float er[2], ei[2];
            #pragma unroll
            for (int k = 0; k < 2; k++) {
                float a = 0.f, bb = 0.f;
                #pragma unroll
                for (int c = 0; c < NC; c++) {
                    a  += wr[c] * rr[c][k] - wi[c] * ii[c][k];
                    bb += wr[c] * ii[c][k] + wi[c] * rr[c][k];
                }
                er[k] = a; ei[k] = bb;
            }
            nfloat4 o0 = {er[0], ei[0], er[1], ei[1]};
            __builtin_nontemporal_store(o0, &o4[p]);
        }
    }
}

extern "C" void kernel_launch(void* const* d_in, const int* in_sizes, int n_in,
                              void* d_out, int out_size, void* d_ws, size_t ws_size,
                              hipStream_t stream) {
    const float* sr = (const float*)d_in[0];
    const float* si = (const float*)d_in[1];
    const float* ms = (const float*)d_in[2];
    const float* mn = (const float*)d_in[3];
    float* out = (float*)d_out;

    float* finbuf = (float*)d_ws;                          // [NG][NACC]
    int*   cnt    = (int*)((char*)d_ws + NG * NACC * sizeof(float));  // [NG]

    // workspace is poisoned between iterations -> re-zero accumulators+counters
    hipMemsetAsync(d_ws, 0, NG * NACC * sizeof(float) + NG * sizeof(int), stream);
    mvdr_onepass<<<NG * NCHUNK, BLK, 0, stream>>>(sr, si, ms, mn, out, finbuf, cnt);
}

// Round 3
// 170.670 us; speedup vs baseline: 6.7036x; 6.7036x over previous
//
#include <hip/hip_runtime.h>

#define NB 4
#define NC 6
#define NF 257
#define NT 2000
#define NG (NB * NF)        // 1028 (b,f) groups
#define NPAIR 15
#define NACC 74             // [0..5] s_diag, [6..11] n_diag, [12+4q..] s_re,s_im,n_re,n_im, [72] sum_ms, [73] sum_mn
#define NCHUNK 4
#define TCH (NT / NCHUNK)   // 500 t per chunk
#define NP2 (TCH / 2)       // 250 float2 positions per chunk
#define BLK 256
#define CS  (NF * NT)       // channel stride (floats)
#define CS2 (CS / 2)        // channel stride (float2)

typedef float nfloat4 __attribute__((ext_vector_type(4)));

// DPP row-shift-right add: lane i += lane (i-N) within its 16-lane row
// (0 beyond row edge). After shr8+shr4+shr2: lane14 = row evens-sum,
// lane15 = row odds-sum (HW-verified in prior session).
template<int CTRL>
__device__ __forceinline__ float dpp_add(float v) {
    int s = __builtin_amdgcn_update_dpp(0, __builtin_bit_cast(int, v), CTRL, 0xF, 0xF, true);
    return v + __builtin_bit_cast(float, s);
}

// upper-triangle pair index for c < e (enumeration matches PC/PE tables)
__device__ __forceinline__ int qidx(int c, int e) {
    return c * (2 * NC - 1 - c) / 2 + (e - c - 1);
}

// ---------------- Kernel A: raw weighted PSD partials per (group, chunk) ----
// EXACT round-0 structure (proven fastest for this phase): 4112 blocks x 256
// threads (~16 waves/CU TLP), one float2 per thread, one 14-load burst,
// small body, no VGPR cap.
__global__ __launch_bounds__(BLK) void psd_kernel(
    const float* __restrict__ sr, const float* __restrict__ si,
    const float* __restrict__ ms, const float* __restrict__ mn,
    float* __restrict__ wsp)
{
    constexpr int PC[NPAIR] = {0,0,0,0,0,1,1,1,1,2,2,2,3,3,4};
    constexpr int PE[NPAIR] = {1,2,3,4,5,2,3,4,5,3,4,5,4,5,5};

    const int bx = blockIdx.x;
    const int g  = bx >> 2;
    const int b  = g / NF;
    const int f  = g - b * NF;
    const int tb = (bx & 3) * TCH;
    const int sbase = b * NC * CS + f * NT + tb;
    const int mbase = g * NT + tb;

    const float2* s2r = (const float2*)(sr + sbase);
    const float2* s2i = (const float2*)(si + sbase);
    const float2* m2s = (const float2*)(ms + mbase);
    const float2* m2n = (const float2*)(mn + mbase);

    float acc[NACC];
    #pragma unroll
    for (int i = 0; i < NACC; i++) acc[i] = 0.f;

    // Unconditional load burst; inactive lanes load p=0 and zero their mask
    // weights (every accumulator term carries a mask factor -> contributes 0).
    const bool act = threadIdx.x < NP2;
    const int  p   = act ? threadIdx.x : 0;
    {
        float wms[2], wmn[2], rr[NC][2], ii[NC][2];
        {
            const float2 t0 = m2s[p];
            wms[0] = t0.x; wms[1] = t0.y;
            const float2 t1 = m2n[p];
            wmn[0] = t1.x; wmn[1] = t1.y;
        }
        #pragma unroll
        for (int c = 0; c < NC; c++) {
            const float2 tr = s2r[c * CS2 + p];
            rr[c][0] = tr.x; rr[c][1] = tr.y;
            const float2 ti = s2i[c * CS2 + p];
            ii[c][0] = ti.x; ii[c][1] = ti.y;
        }
        if (!act) { wms[0] = wms[1] = wmn[0] = wmn[1] = 0.f; }
        #pragma unroll
        for (int k = 0; k < 2; k++) { acc[72] += wms[k]; acc[73] += wmn[k]; }
        #pragma unroll
        for (int c = 0; c < NC; c++) {
            #pragma unroll
            for (int k = 0; k < 2; k++) {
                const float d = rr[c][k] * rr[c][k] + ii[c][k] * ii[c][k];
                acc[c]     += d * wms[k];
                acc[6 + c] += d * wmn[k];
            }
        }
        #pragma unroll
        for (int q = 0; q < NPAIR; q++) {
            const int c = PC[q], e = PE[q];
            #pragma unroll
            for (int k = 0; k < 2; k++) {
                const float cr = rr[c][k] * rr[e][k] + ii[c][k] * ii[e][k];
                const float ci = ii[c][k] * rr[e][k] - rr[c][k] * ii[e][k];
                acc[12 + 4 * q + 0] += cr * wms[k];
                acc[12 + 4 * q + 1] += ci * wms[k];
                acc[12 + 4 * q + 2] += cr * wmn[k];
                acc[12 + 4 * q + 3] += ci * wmn[k];
            }
        }
    }

    // In-row DPP reduction (VALU pipe): lane14 = row evens-sum, lane15 = odds.
    #pragma unroll
    for (int i = 0; i < NACC; i++) {
        float v = acc[i];
        v = dpp_add<0x118>(v);   // row_shr:8
        v = dpp_add<0x114>(v);   // row_shr:4
        v = dpp_add<0x112>(v);   // row_shr:2
        acc[i] = v;
    }

    __shared__ float red[32][NACC];
    const int lane16 = threadIdx.x & 15;
    const int ridx   = ((threadIdx.x >> 4) << 1) | (lane16 & 1);  // 0..31
    if (lane16 >= 14) {
        #pragma unroll
        for (int i = 0; i < NACC; i++) red[ridx][i] = acc[i];
    }
    __syncthreads();

    if (threadIdx.x < NACC) {
        float s = 0.f;
        #pragma unroll
        for (int r = 0; r < 32; r++) s += red[r][threadIdx.x];
        wsp[bx * NACC + threadIdx.x] = s;
    }
}

// ---------------- Kernel B: fused solve + apply -----------------------------
// 4112 blocks x 256. Head: each block redundantly sums its group's 4 partial
// rows (1184 B, L2-hot), lane-parallel complex LU on lanes 0..5 (one RHS
// column per lane — code verified in round 1), w broadcast via LDS.
// Tail: round-0 apply over this block's 500-t chunk (spec re-read L3-hot).
// Eliminates the separate 17-block solve dispatch + its launch gap + the
// wsw round-trip.
__global__ __launch_bounds__(BLK) void solve_apply_kernel(
    const float* __restrict__ sr, const float* __restrict__ si,
    const float* __restrict__ wsp, float* __restrict__ out)
{
    constexpr int PC[NPAIR] = {0,0,0,0,0,1,1,1,1,2,2,2,3,3,4};
    constexpr int PE[NPAIR] = {1,2,3,4,5,2,3,4,5,3,4,5,4,5,5};

    const int bx = blockIdx.x;
    const int g  = bx >> 2;
    const int b  = g / NF;
    const int f  = g - b * NF;
    const int tb = (bx & 3) * TCH;
    const int sbase = b * NC * CS + f * NT + tb;
    const int tid = threadIdx.x;

    __shared__ float fin[NACC];
    __shared__ float sdr[NC], sdi[NC];
    __shared__ float wsh[2 * NC];

    // group reduction of the 4 chunk partials (L2-hot reads)
    const float* p0 = wsp + (4 * g) * NACC;
    if (tid < NACC) {
        fin[tid] = (p0[tid] + p0[NACC + tid]) + (p0[2 * NACC + tid] + p0[3 * NACC + tid]);
    }
    __syncthreads();

    // ---------------- lane-parallel solve (lanes 0..5) ---------------------
    float xr[NC], xi[NC];
    if (tid < NC) {
        const float invS = 1.f / (fin[72] + 1e-15f);
        const float invN = 1.f / (fin[73] + 1e-15f);

        // A = normalized psd_n + eps*I
        float Ar[NC][NC], Ai[NC][NC];
        #pragma unroll
        for (int c = 0; c < NC; c++) { Ar[c][c] = fin[6 + c] * invN; Ai[c][c] = 0.f; }
        #pragma unroll
        for (int q = 0; q < NPAIR; q++) {
            const int c = PC[q], e = PE[q];
            const float nre = fin[12 + 4 * q + 2] * invN;
            const float nim = fin[12 + 4 * q + 3] * invN;
            Ar[c][e] = nre;  Ai[c][e] = nim;
            Ar[e][c] = nre;  Ai[e][c] = -nim;
        }
        {
            float trn = 0.f;
            #pragma unroll
            for (int c = 0; c < NC; c++) trn += Ar[c][c];
            const float eps = trn * 1e-7f + 1e-8f;
            #pragma unroll
            for (int c = 0; c < NC; c++) Ar[c][c] += eps;
        }

        // In-place unpivoted LU (redundant on each of the 6 lanes)
        #pragma unroll
        for (int k = 0; k < NC; k++) {
            const float dr = Ar[k][k], di = Ai[k][k];
            const float idn = 1.f / (dr * dr + di * di);
            const float pr = dr * idn, pi = -di * idn;
            #pragma unroll
            for (int i = k + 1; i < NC; i++) {
                const float lr = Ar[i][k] * pr - Ai[i][k] * pi;
                const float li = Ar[i][k] * pi + Ai[i][k] * pr;
                Ar[i][k] = lr; Ai[i][k] = li;
                #pragma unroll
                for (int j = k + 1; j < NC; j++) {
                    Ar[i][j] -= lr * Ar[k][j] - li * Ai[k][j];
                    Ai[i][j] -= lr * Ai[k][j] + li * Ar[k][j];
                }
            }
        }

        // RHS = column `tid` of normalized psd_s (i compile-time, tid runtime)
        #pragma unroll
        for (int i = 0; i < NC; i++) {
            if (i == tid)      { xr[i] = fin[i] * invS;  xi[i] = 0.f; }
            else if (i < tid)  { const int q = qidx(i, tid);
                                 xr[i] = fin[12 + 4 * q] * invS;  xi[i] =  fin[13 + 4 * q] * invS; }
            else               { const int q = qidx(tid, i);
                                 xr[i] = fin[12 + 4 * q] * invS;  xi[i] = -fin[13 + 4 * q] * invS; }
        }
        // forward substitution
        #pragma unroll
        for (int i = 1; i < NC; i++) {
            #pragma unroll
            for (int k = 0; k < NC - 1; k++) if (k < i) {
                xr[i] -= Ar[i][k] * xr[k] - Ai[i][k] * xi[k];
                xi[i] -= Ar[i][k] * xi[k] + Ai[i][k] * xr[k];
            }
        }
        // backward substitution
        #pragma unroll
        for (int i = NC - 1; i >= 0; i--) {
            #pragma unroll
            for (int k = 0; k < NC; k++) if (k > i) {
                xr[i] -= Ar[i][k] * xr[k] - Ai[i][k] * xi[k];
                xi[i] -= Ar[i][k] * xi[k] + Ai[i][k] * xr[k];
            }
            const float dr = Ar[i][i], di = Ai[i][i];
            const float idn = 1.f / (dr * dr + di * di);
            const float pr = dr * idn, pi = -di * idn;
            const float t0 = xr[i] * pr - xi[i] * pi;
            xi[i] = xr[i] * pi + xi[i] * pr;
            xr[i] = t0;
        }
        // own diagonal element, extracted without runtime register indexing
        float dgr = xr[0], dgi = xi[0];
        #pragma unroll
        for (int i = 1; i < NC; i++) if (tid == i) { dgr = xr[i]; dgi = xi[i]; }
        sdr[tid] = dgr; sdi[tid] = dgi;
    }
    __syncthreads();

    if (tid == 0) {
        float trr = 1e-8f, tri = 0.f;   // TIK_EPS on real part of trace
        #pragma unroll
        for (int c = 0; c < NC; c++) { trr += sdr[c]; tri += sdi[c]; }
        const float idn = 1.f / (trr * trr + tri * tri);
        #pragma unroll
        for (int c = 0; c < NC; c++) {
            // lane 0's xr/xi == column 0 of the numerator (persists across barrier)
            const float wre = (xr[c] * trr + xi[c] * tri) * idn;
            const float wim = (xi[c] * trr - xr[c] * tri) * idn;
            wsh[c]     = wre;    // conj(w): real
            wsh[6 + c] = -wim;   // conj(w): imag
        }
    }
    __syncthreads();

    // ---------------- apply w over this block's chunk ----------------------
    float wr[NC], wi[NC];
    #pragma unroll
    for (int c = 0; c < NC; c++) { wr[c] = wsh[c]; wi[c] = wsh[6 + c]; }

    const float2* s2r = (const float2*)(sr + sbase);
    const float2* s2i = (const float2*)(si + sbase);
    nfloat4* o4 = (nfloat4*)(out + 2 * (g * NT + tb));

    const int p = tid;
    if (p < NP2) {
        float rr[NC][2], ii[NC][2];
        #pragma unroll
        for (int c = 0; c < NC; c++) {
            const float2 tr = s2r[c * CS2 + p];
            rr[c][0] = tr.x; rr[c][1] = tr.y;
            const float2 ti = s2i[c * CS2 + p];
            ii[c][0] = ti.x; ii[c][1] = ti.y;
        }
        float er[2], ei[2];
        #pragma unroll
        for (int k = 0; k < 2; k++) {
            float a = 0.f, bb = 0.f;
            #pragma unroll
            for (int c = 0; c < NC; c++) {
                a  += wr[c] * rr[c][k] - wi[c] * ii[c][k];
                bb += wr[c] * ii[c][k] + wi[c] * rr[c][k];
            }
            er[k] = a; ei[k] = bb;
        }
        nfloat4 o0 = {er[0], ei[0], er[1], ei[1]};
        __builtin_nontemporal_store(o0, &o4[p]);
    }
}

extern "C" void kernel_launch(void* const* d_in, const int* in_sizes, int n_in,
                              void* d_out, int out_size, void* d_ws, size_t ws_size,
                              hipStream_t stream) {
    const float* sr = (const float*)d_in[0];
    const float* si = (const float*)d_in[1];
    const float* ms = (const float*)d_in[2];
    const float* mn = (const float*)d_in[3];
    float* out = (float*)d_out;

    float* wsp = (float*)d_ws;   // [NG*NCHUNK][NACC] partials (fully rewritten each call)

    psd_kernel<<<NG * NCHUNK, BLK, 0, stream>>>(sr, si, ms, mn, wsp);
    solve_apply_kernel<<<NG * NCHUNK, BLK, 0, stream>>>(sr, si, wsp, out);
}